// Round 7
// baseline (300.141 us; speedup 1.0000x reference)
//
#include <hip/hip_runtime.h>
#include <math.h>

// MultiHeadedAttention  B=2, S=2048, D=1024, H=16, DH=64 (fp32 in/out)
// R6: attn in-block split-K. 512 thr / 8 waves: wave=(qg,kh) does q-rows
// qg*16..+15 over k-half kh (fixed-max softmax => partials combine by plain
// add). 2 K/V LDS sets + 8 P tiles = 52KB -> 3 blocks/CU = 24 waves/CU
// (was grid-limited ~2.7 blocks * 4 waves). Epilogue combine via LDS.
// ws: Qbf@0 Kbf@8M Vt@16M mpk@32M Whi@33M ctxHi@41M ctxLo@49M

constexpr int Bc  = 2;
constexpr int Sc  = 2048;
constexpr int Dc  = 1024;
constexpr int Hc  = 16;
constexpr int DHc = 64;
constexpr int BSc = Bc * Sc;     // 4096

constexpr float LOG2E = 1.4426950408889634f;

typedef __bf16 bf16x8 __attribute__((ext_vector_type(8)));
typedef __bf16 bf16x4 __attribute__((ext_vector_type(4)));
typedef float  f32x4  __attribute__((ext_vector_type(4)));

#define GLDS16(gp, lp) __builtin_amdgcn_global_load_lds( \
    (const __attribute__((address_space(1))) void*)(gp), \
    (__attribute__((address_space(3))) void*)(lp), 16, 0, 0)

// ---------------------------------------------------------------------------
// Weight cast: Whi[z] = RNE bf16 of {Wq,Wk,Wv,Wo}
// ---------------------------------------------------------------------------
__global__ __launch_bounds__(256)
void wsplit(const float* __restrict__ W0, const float* __restrict__ W1,
            const float* __restrict__ W2, const float* __restrict__ W3,
            __bf16* __restrict__ out)
{
    const float* src[4] = {W0, W1, W2, W3};
    const int z = blockIdx.y;
    const size_t idx = ((size_t)blockIdx.x * 256 + threadIdx.x) * 4;
    const float4 v = *(const float4*)&src[z][idx];
    bf16x4 o;
    o[0] = (__bf16)v.x; o[1] = (__bf16)v.y; o[2] = (__bf16)v.z; o[3] = (__bf16)v.w;
    *(bf16x4*)&out[(size_t)z * Dc * Dc + idx] = o;
}

// ---------------------------------------------------------------------------
// Single-pass K-sweep, M-tile 128: acc += bf16(A)*W.
// ---------------------------------------------------------------------------
__device__ __forceinline__ void sweep128s(const float* __restrict__ A,
                                          const __bf16* __restrict__ Wh,
                                          __bf16* As, __bf16* Ws,
                                          int gm0, int gn0, f32x4 acc[4][4])
{
    const int tid  = threadIdx.x;
    const int w    = tid >> 6;
    const int lane = tid & 63;
    const int cc   = lane & 15;
    const int g    = lane >> 4;
    const int wm   = (w & 1) * 64;
    const int wn   = (w >> 1) * 64;

    for (int k0 = 0; k0 < Dc; k0 += 64) {
        __syncthreads();
#pragma unroll
        for (int r = 0; r < 4; ++r) {
            const int L  = r * 256 + tid;
            const int wr = L >> 3;
            const int sl = L & 7;
            const int c  = sl ^ (wr & 7);
            GLDS16(Wh + (size_t)(gn0 + wr) * Dc + k0 + c * 8,
                   (char*)Ws + (r * 256 + w * 64) * 16);
        }
#pragma unroll
        for (int i = 0; i < 8; ++i) {
            const int Lq = i * 256 + tid;
            const int ar = Lq >> 4;
            const int aq = Lq & 15;
            const float4 v = *(const float4*)&A[(size_t)(gm0 + ar) * Dc + k0 + aq * 4];
            const int off = ar * 128 +
                        ((((aq >> 1) ^ (ar & 7)) << 4) | ((aq & 1) << 3));
            bf16x4 hv;   // RNE
            hv[0] = (__bf16)v.x; hv[1] = (__bf16)v.y;
            hv[2] = (__bf16)v.z; hv[3] = (__bf16)v.w;
            *(bf16x4*)((char*)As + off) = hv;
        }
        __syncthreads();
#pragma unroll
        for (int kk = 0; kk < 2; ++kk) {
            const int cb4 = (kk * 4 + g) << 4;
            bf16x8 af[4], bfr[4];
#pragma unroll
            for (int mt = 0; mt < 4; ++mt) {
                const int row = wm + mt * 16 + cc;
                af[mt] = *(const bf16x8*)((const char*)As + row * 128 +
                                          (cb4 ^ ((row & 7) << 4)));
            }
#pragma unroll
            for (int nt = 0; nt < 4; ++nt) {
                const int row = wn + nt * 16 + cc;
                bfr[nt] = *(const bf16x8*)((const char*)Ws + row * 128 +
                                           (cb4 ^ ((row & 7) << 4)));
            }
#pragma unroll
            for (int mt = 0; mt < 4; ++mt)
#pragma unroll
                for (int nt = 0; nt < 4; ++nt)
                    acc[mt][nt] = __builtin_amdgcn_mfma_f32_16x16x32_bf16(
                        af[mt], bfr[nt], acc[mt][nt], 0, 0, 0);
        }
    }
}

// ---------------------------------------------------------------------------
// hi/lo K-sweep, M64, all operands bf16 staged via global_load_lds.
// ---------------------------------------------------------------------------
__device__ __forceinline__ void sweep64b(const __bf16* __restrict__ Ahi,
                                         const __bf16* __restrict__ Alo,
                                         const __bf16* __restrict__ Wh,
                                         __bf16* AsHi, __bf16* AsLo, __bf16* Ws,
                                         int gm0, int gn0, f32x4 acc[2][4])
{
    const int tid  = threadIdx.x;
    const int w    = tid >> 6;
    const int lane = tid & 63;
    const int cc   = lane & 15;
    const int g    = lane >> 4;
    const int wm   = (w & 1) * 32;
    const int wn   = (w >> 1) * 64;

    for (int k0 = 0; k0 < Dc; k0 += 64) {
        __syncthreads();
#pragma unroll
        for (int r = 0; r < 4; ++r) {
            const int L  = r * 256 + tid;
            const int wr = L >> 3;
            const int sl = L & 7;
            const int c  = sl ^ (wr & 7);
            GLDS16(Wh + (size_t)(gn0 + wr) * Dc + k0 + c * 8,
                   (char*)Ws + (r * 256 + w * 64) * 16);
        }
#pragma unroll
        for (int r = 0; r < 2; ++r) {
            const int L  = r * 256 + tid;
            const int wr = L >> 3;
            const int sl = L & 7;
            const int c  = sl ^ (wr & 7);
            GLDS16(Ahi + (size_t)(gm0 + wr) * Dc + k0 + c * 8,
                   (char*)AsHi + (r * 256 + w * 64) * 16);
            GLDS16(Alo + (size_t)(gm0 + wr) * Dc + k0 + c * 8,
                   (char*)AsLo + (r * 256 + w * 64) * 16);
        }
        __syncthreads();
#pragma unroll
        for (int kk = 0; kk < 2; ++kk) {
            const int cb4 = (kk * 4 + g) << 4;
            bf16x8 ahi[2], alo[2], bfr[4];
#pragma unroll
            for (int mt = 0; mt < 2; ++mt) {
                const int row = wm + mt * 16 + cc;
                const int off = row * 128 + (cb4 ^ ((row & 7) << 4));
                ahi[mt] = *(const bf16x8*)((const char*)AsHi + off);
                alo[mt] = *(const bf16x8*)((const char*)AsLo + off);
            }
#pragma unroll
            for (int nt = 0; nt < 4; ++nt) {
                const int row = wn + nt * 16 + cc;
                bfr[nt] = *(const bf16x8*)((const char*)Ws + row * 128 +
                                           (cb4 ^ ((row & 7) << 4)));
            }
#pragma unroll
            for (int mt = 0; mt < 2; ++mt)
#pragma unroll
                for (int nt = 0; nt < 4; ++nt) {
                    acc[mt][nt] = __builtin_amdgcn_mfma_f32_16x16x32_bf16(
                        ahi[mt], bfr[nt], acc[mt][nt], 0, 0, 0);
                    acc[mt][nt] = __builtin_amdgcn_mfma_f32_16x16x32_bf16(
                        alo[mt], bfr[nt], acc[mt][nt], 0, 0, 0);
                }
        }
    }
}

// ---------------------------------------------------------------------------
// QKV projection. z==2 writes V^T [BH,DH,S] directly (packed b64 stores).
// ---------------------------------------------------------------------------
__global__ __launch_bounds__(256)
void qkv_mfma(const float* __restrict__ query, const float* __restrict__ key,
              const float* __restrict__ value, const __bf16* __restrict__ Whi,
              const float* __restrict__ bq, const float* __restrict__ bk,
              const float* __restrict__ bv,
              __bf16* __restrict__ Qo, __bf16* __restrict__ Ko, __bf16* __restrict__ Vt)
{
    __shared__ __align__(16) __bf16 As[8192];
    __shared__ __align__(16) __bf16 Ws[8192];

    const int z = blockIdx.z;
    const float* A    = (z == 0) ? query : (z == 1) ? key : value;
    const float* bias = (z == 0) ? bq    : (z == 1) ? bk  : bv;
    const float scale = (z == 0) ? 0.125f * LOG2E : 1.0f;
    const __bf16* Wh  = Whi + (size_t)z * Dc * Dc;

    const int gm0 = blockIdx.x * 128;
    const int gn0 = blockIdx.y * 128;

    f32x4 acc[4][4];
#pragma unroll
    for (int mt = 0; mt < 4; ++mt)
#pragma unroll
        for (int nt = 0; nt < 4; ++nt) acc[mt][nt] = {0.f, 0.f, 0.f, 0.f};

    sweep128s(A, Wh, As, Ws, gm0, gn0, acc);

    const int tid = threadIdx.x;
    const int w = tid >> 6, lane = tid & 63;
    const int cc = lane & 15, g = lane >> 4;
    const int wm = (w & 1) * 64, wn = (w >> 1) * 64;

    float bias4[4];
#pragma unroll
    for (int nt = 0; nt < 4; ++nt) bias4[nt] = bias[gn0 + wn + nt * 16 + cc];

    if (z == 2) {
        // V^T epilogue: 4 regs = 4 consecutive s at fixed dh -> b64 store
#pragma unroll
        for (int mt = 0; mt < 4; ++mt)
#pragma unroll
            for (int nt = 0; nt < 4; ++nt) {
                const int col = gn0 + wn + nt * 16 + cc;
                const int h = col >> 6, dh = col & 63;
                const int row0 = gm0 + wm + mt * 16 + g * 4;
                const int b = row0 >> 11, s0 = row0 & 2047;
                bf16x4 vv;
#pragma unroll
                for (int reg = 0; reg < 4; ++reg)
                    vv[reg] = (__bf16)(acc[mt][nt][reg] + bias4[nt]);
                *(bf16x4*)&Vt[(((size_t)(b * Hc + h)) * DHc + dh) * Sc + s0] = vv;
            }
    } else {
        __bf16* O = (z == 0) ? Qo : Ko;
#pragma unroll
        for (int mt = 0; mt < 4; ++mt)
#pragma unroll
            for (int nt = 0; nt < 4; ++nt) {
                const int col = gn0 + wn + nt * 16 + cc;
                const int h = col >> 6, dh = col & 63;
#pragma unroll
                for (int reg = 0; reg < 4; ++reg) {
                    const int row = gm0 + wm + mt * 16 + g * 4 + reg;
                    const int b = row >> 11, s = row & 2047;
                    O[(((size_t)(b * Hc + h)) * Sc + s) * DHc + dh] =
                        (__bf16)((acc[mt][nt][reg] + bias4[nt]) * scale);
                }
            }
    }
}

// ---------------------------------------------------------------------------
// Output projection: out = (ctxHi+ctxLo) @ Wo^T + bo, fp32 out.
// ---------------------------------------------------------------------------
__global__ __launch_bounds__(256)
void out_mfma(const __bf16* __restrict__ ctxHi, const __bf16* __restrict__ ctxLo,
              const __bf16* __restrict__ Wohi,
              const float* __restrict__ bo, float* __restrict__ out)
{
    __shared__ __align__(16) __bf16 AsHi[4096];
    __shared__ __align__(16) __bf16 AsLo[4096];
    __shared__ __align__(16) __bf16 Ws[8192];

    const int gm0 = blockIdx.x * 64;
    const int gn0 = blockIdx.y * 128;

    f32x4 acc[2][4];
#pragma unroll
    for (int mt = 0; mt < 2; ++mt)
#pragma unroll
        for (int nt = 0; nt < 4; ++nt) acc[mt][nt] = {0.f, 0.f, 0.f, 0.f};

    sweep64b(ctxHi, ctxLo, Wohi, AsHi, AsLo, Ws, gm0, gn0, acc);

    const int tid = threadIdx.x;
    const int w = tid >> 6, lane = tid & 63;
    const int cc = lane & 15, g = lane >> 4;
    const int wm = (w & 1) * 32, wn = (w >> 1) * 64;

    float bias4[4];
#pragma unroll
    for (int nt = 0; nt < 4; ++nt) bias4[nt] = bo[gn0 + wn + nt * 16 + cc];

#pragma unroll
    for (int mt = 0; mt < 2; ++mt)
#pragma unroll
        for (int nt = 0; nt < 4; ++nt) {
            const int col = gn0 + wn + nt * 16 + cc;
#pragma unroll
            for (int reg = 0; reg < 4; ++reg) {
                const int row = gm0 + wm + mt * 16 + g * 4 + reg;
                out[(size_t)row * Dc + col] = acc[mt][nt][reg] + bias4[nt];
            }
        }
}

// ---------------------------------------------------------------------------
// Bitpack mask: each wave packs 4 u64 words (256 elements).
// ---------------------------------------------------------------------------
__global__ __launch_bounds__(256)
void mask_pack(const int* __restrict__ mask, unsigned long long* __restrict__ out)
{
    const int lane = threadIdx.x & 63;
    const size_t waveBase = ((size_t)blockIdx.x * 4 + (threadIdx.x >> 6)) * 256;
    unsigned long long b0 = __ballot(mask[waveBase + lane]        != 0);
    unsigned long long b1 = __ballot(mask[waveBase + 64 + lane]   != 0);
    unsigned long long b2 = __ballot(mask[waveBase + 128 + lane]  != 0);
    unsigned long long b3 = __ballot(mask[waveBase + 192 + lane]  != 0);
    if (lane == 0) {
        unsigned long long* dst = out + (waveBase >> 6);
        dst[0] = b0; dst[1] = b1; dst[2] = b2; dst[3] = b3;
    }
}

// ---------------------------------------------------------------------------
// Flash attention, in-block split-K. 512 threads = 8 waves:
// wave w = (qg = w&3: 16 q-rows, kh = w>>2: k-half). Fixed-max exp2 softmax
// => partial (o,l) from the two halves combine by plain addition (exact).
// LDS: 2 K/V sets (one per half) @ kh*18432, P tiles @36864 + w*2048 = 52KB
// -> 3 blocks/CU = 24 waves/CU. Epilogue: kh=1 dumps partials into dead
// K/V-set0 region; kh=0 adds, normalizes, stores ctx hi/lo.
// ---------------------------------------------------------------------------
__global__ __launch_bounds__(512, 6)
void attn_mfma(const __bf16* __restrict__ Q, const __bf16* __restrict__ K,
               const __bf16* __restrict__ Vt,
               const unsigned long long* __restrict__ mp,
               __bf16* __restrict__ ctxHi, __bf16* __restrict__ ctxLo)
{
    __shared__ __align__(16) char smem[53248];

    const int tid  = threadIdx.x;
    const int w    = tid >> 6;       // 0..7
    const int lane = tid & 63;
    const int cc   = lane & 15;
    const int g    = lane >> 4;
    const int qg   = w & 3;
    const int kh   = w >> 2;
    const int bh   = blockIdx.y;
    const int b    = bh >> 4;
    const int h    = bh & 15;
    const int qw   = blockIdx.x * 64 + qg * 16;

    const __bf16* Qb  = Q  + (size_t)bh * Sc * DHc;
    const __bf16* Kb  = K  + (size_t)bh * Sc * DHc;
    const __bf16* Vtb = Vt + (size_t)bh * DHc * Sc;

    __bf16* Ks = (__bf16*)(smem + kh * 18432);           // [64][72]
    __bf16* Vs = (__bf16*)(smem + kh * 18432 + 9216);    // [64][72]
    char*   Pw = smem + 36864 + w * 2048;

    const bf16x8 qa0 = *(const bf16x8*)&Qb[(size_t)(qw + cc) * DHc + g * 8];
    const bf16x8 qa1 = *(const bf16x8*)&Qb[(size_t)(qw + cc) * DHc + 32 + g * 8];

    f32x4 o[4] = {};
    float l[4] = {0.f, 0.f, 0.f, 0.f};

    const int t4    = tid & 255;        // index within 4-wave k-half group
    const int str_r = t4 >> 3;          // 0..31
    const int str_c = (t4 & 7) * 8;     // 0..56
    const int kbase = kh * (Sc / 2);

    bf16x8 pk0 = *(const bf16x8*)&Kb[(size_t)(kbase + str_r) * DHc + str_c];
    bf16x8 pk1 = *(const bf16x8*)&Kb[(size_t)(kbase + str_r + 32) * DHc + str_c];
    bf16x8 pv0 = *(const bf16x8*)&Vtb[(size_t)str_r * Sc + kbase + str_c];
    bf16x8 pv1 = *(const bf16x8*)&Vtb[(size_t)(str_r + 32) * Sc + kbase + str_c];

    for (int it = 0; it < 16; ++it) {
        const int k0 = kbase + it * 64;
        __syncthreads();
        *(bf16x8*)&Ks[(size_t)str_r * 72 + str_c]        = pk0;
        *(bf16x8*)&Ks[(size_t)(str_r + 32) * 72 + str_c] = pk1;
        *(bf16x8*)&Vs[(size_t)str_r * 72 + str_c]        = pv0;
        *(bf16x8*)&Vs[(size_t)(str_r + 32) * 72 + str_c] = pv1;
        __syncthreads();

        if (it < 15) {
            const int kn = k0 + 64;
            pk0 = *(const bf16x8*)&Kb[(size_t)(kn + str_r) * DHc + str_c];
            pk1 = *(const bf16x8*)&Kb[(size_t)(kn + str_r + 32) * DHc + str_c];
            pv0 = *(const bf16x8*)&Vtb[(size_t)str_r * Sc + kn + str_c];
            pv1 = *(const bf16x8*)&Vtb[(size_t)(str_r + 32) * Sc + kn + str_c];
        }

        unsigned long long mw[4];
#pragma unroll
        for (int r = 0; r < 4; ++r)
            mw[r] = mp[(size_t)(b * Sc + qw + g * 4 + r) * (Sc / 64) + (k0 >> 6)];

        f32x4 sc[4];
#pragma unroll
        for (int nt = 0; nt < 4; ++nt) {
            const bf16x8 kb0 = *(const bf16x8*)&Ks[(size_t)(nt * 16 + cc) * 72 + g * 8];
            const bf16x8 kb1 = *(const bf16x8*)&Ks[(size_t)(nt * 16 + cc) * 72 + 32 + g * 8];
            f32x4 z = {-24.f, -24.f, -24.f, -24.f};
            z = __builtin_amdgcn_mfma_f32_16x16x32_bf16(qa0, kb0, z, 0, 0, 0);
            z = __builtin_amdgcn_mfma_f32_16x16x32_bf16(qa1, kb1, z, 0, 0, 0);
            sc[nt] = z;
        }

        unsigned mlo[4], mhi[4];
#pragma unroll
        for (int r = 0; r < 4; ++r) {
            const unsigned long long sh = mw[r] >> cc;
            mlo[r] = (unsigned)sh;
            mhi[r] = (unsigned)(sh >> 32);
        }
#pragma unroll
        for (int nt = 0; nt < 4; ++nt)
#pragma unroll
            for (int r = 0; r < 4; ++r) {
                float p = __builtin_amdgcn_exp2f(sc[nt][r]);
                const unsigned bit =
                    (nt == 0) ? (mlo[r] & 1u) :
                    (nt == 1) ? (mlo[r] & 0x10000u) :
                    (nt == 2) ? (mhi[r] & 1u) : (mhi[r] & 0x10000u);
                p = bit ? 0.f : p;
                l[r] += p;
                *(__bf16*)(Pw + (g * 4 + r) * 128 + (((nt ^ g) << 5) | (cc << 1))) =
                    (__bf16)p;
            }

        const int sw = (cc >> 2) << 5;
        const bf16x8 pa0 = *(const bf16x8*)(Pw + cc * 128 + ((g * 16) ^ sw));
        const bf16x8 pa1 = *(const bf16x8*)(Pw + cc * 128 + ((64 + g * 16) ^ sw));

#pragma unroll
        for (int nt = 0; nt < 4; ++nt) {
            const bf16x8 vb0 = *(const bf16x8*)&Vs[(size_t)(nt * 16 + cc) * 72 + g * 8];
            const bf16x8 vb1 = *(const bf16x8*)&Vs[(size_t)(nt * 16 + cc) * 72 + 32 + g * 8];
            o[nt] = __builtin_amdgcn_mfma_f32_16x16x32_bf16(pa0, vb0, o[nt], 0, 0, 0);
            o[nt] = __builtin_amdgcn_mfma_f32_16x16x32_bf16(pa1, vb1, o[nt], 0, 0, 0);
        }
    }

    // per-half l reduction across the 16-lane cc group
#pragma unroll
    for (int off = 1; off < 16; off <<= 1)
#pragma unroll
        for (int r = 0; r < 4; ++r)
            l[r] += __shfl_xor(l[r], off, 16);

    // combine halves via LDS (K/V-set0 region is dead now)
    __syncthreads();
    float* Oc = (float*)smem;              // [64][64] fp32 = 16KB
    float* Lc = (float*)(smem + 16384);    // [64] fp32
    if (kh) {
#pragma unroll
        for (int nt = 0; nt < 4; ++nt)
#pragma unroll
            for (int r = 0; r < 4; ++r)
                Oc[(qg * 16 + g * 4 + r) * 64 + nt * 16 + cc] = o[nt][r];
        if (cc == 0)
#pragma unroll
            for (int r = 0; r < 4; ++r) Lc[qg * 16 + g * 4 + r] = l[r];
    }
    __syncthreads();
    if (!kh) {
#pragma unroll
        for (int r = 0; r < 4; ++r) {
            const float lt = l[r] + Lc[qg * 16 + g * 4 + r];
            const float inv = 1.0f / lt;
            const int q = qw + g * 4 + r;
#pragma unroll
            for (int nt = 0; nt < 4; ++nt) {
                const size_t idx = ((size_t)b * Sc + q) * Dc + h * 64 + nt * 16 + cc;
                const float v =
                    (o[nt][r] + Oc[(qg * 16 + g * 4 + r) * 64 + nt * 16 + cc]) * inv;
                const __bf16 hi = (__bf16)v;
                ctxHi[idx] = hi;
                ctxLo[idx] = (__bf16)(v - (float)hi);
            }
        }
    }
}

extern "C" void kernel_launch(void* const* d_in, const int* in_sizes, int n_in,
                              void* d_out, int out_size, void* d_ws, size_t ws_size,
                              hipStream_t stream)
{
    const float* key   = (const float*)d_in[0];
    const float* value = (const float*)d_in[1];
    const float* query = (const float*)d_in[2];
    const int*   mask  = (const int*)  d_in[3];
    const float* Wq    = (const float*)d_in[4];
    const float* bq    = (const float*)d_in[5];
    const float* Wk    = (const float*)d_in[6];
    const float* bk    = (const float*)d_in[7];
    const float* Wv    = (const float*)d_in[8];
    const float* bv    = (const float*)d_in[9];
    const float* Wo    = (const float*)d_in[10];
    const float* bo    = (const float*)d_in[11];
    float* out = (float*)d_out;

    char* wsb = (char*)d_ws;
    __bf16* Qbf  = (__bf16*)(wsb);
    __bf16* Kbf  = (__bf16*)(wsb + ((size_t)8  << 20));
    __bf16* Vt   = (__bf16*)(wsb + ((size_t)16 << 20));
    unsigned long long* mpk = (unsigned long long*)(wsb + ((size_t)32 << 20));
    __bf16* Whi  = (__bf16*)(wsb + ((size_t)33 << 20));
    __bf16* ctxHi = (__bf16*)(wsb + ((size_t)41 << 20));
    __bf16* ctxLo = (__bf16*)(wsb + ((size_t)49 << 20));

    dim3 gws(Dc * Dc / (256 * 4), 4);
    wsplit<<<gws, 256, 0, stream>>>(Wq, Wk, Wv, Wo, Whi);

    dim3 gqkv(BSc / 128, Dc / 128, 3);
    qkv_mfma<<<gqkv, 256, 0, stream>>>(query, key, value, Whi, bq, bk, bv,
                                       Qbf, Kbf, Vt);

    const int mask_n = Bc * Sc * Sc;
    mask_pack<<<mask_n / 1024, 256, 0, stream>>>(mask, mpk);

    dim3 gattn(Sc / 64, Bc * Hc);
    attn_mfma<<<gattn, 512, 0, stream>>>(Qbf, Kbf, Vt, mpk, ctxHi, ctxLo);

    dim3 gout(BSc / 64, Dc / 128);
    out_mfma<<<gout, 256, 0, stream>>>(ctxHi, ctxLo, Whi + (size_t)3 * Dc * Dc,
                                       bo, out);
}